// Round 11
// baseline (140.276 us; speedup 1.0000x reference)
//
#include <hip/hip_runtime.h>
#include <math.h>

#define NN   100000
#define NE   1600000
#define IND  128
#define OUTD 64

#define BK_NODES 64                      // nodes per bucket
#define NBUCK    1563                    // ceil(NN / 64); 1563*64 = 100032
#define CAPB     1280                    // edge capacity per bucket (mean 1024, +8 sigma)
#define CAPN     64                      // per-node slots in LDS (P(deg>64)~1e-14, Poisson(16))

// ---------------- ws layout (4-byte words) ----------------
#define OFF_Z      0                          // NN*OUTD bf16 = NN*32 words
#define OFF_SSRC   (OFF_Z + NN * OUTD / 2)    // NN f32
#define OFF_SDST   (OFF_SSRC + NN)            // NN f32
#define OFF_BCNT   (OFF_SDST + NN)            // NBUCK i32
#define OFF_COARSE (OFF_BCNT + NBUCK)         // NBUCK*CAPB u32 packed (src<<6 | dstLocal)
// total ~= 13.6 + 8.0 ~= 22 MB

// merged pre-pass geometry: bin blocks first, then zs blocks
#define BIN_EPT     8
#define BIN_BLOCKS  782                  // 782*256*8 = 1,601,536 >= NE
#define ZS_BLOCKS   1563                 // ceil(NN/64)
#define PRE_BLOCKS  (BIN_BLOCKS + ZS_BLOCKS)

__device__ __forceinline__ unsigned short f32_to_bf16_rne(float x)
{
    unsigned int b = __float_as_uint(x);
    b += 0x7FFFu + ((b >> 16) & 1u);
    return (unsigned short)(b >> 16);
}

// ---------------- merged pre-pass: bin branch + zs branch ----------------
__global__ void __launch_bounds__(256) k_pre(
    const float* __restrict__ h, const float* __restrict__ W,
    const float* __restrict__ a, const int* __restrict__ src,
    const int* __restrict__ dst, unsigned short* __restrict__ z16,
    float* __restrict__ s_src, float* __restrict__ s_dst,
    int* __restrict__ bcnt, unsigned int* __restrict__ coarse)
{
    __shared__ float4 smem[64 * 33];          // 33.8 KB union
    int t = threadIdx.x;

    if (blockIdx.x < BIN_BLOCKS) {
        // ---- bin branch: bucket edges by dst>>6, LDS hist + clustered scatter ----
        int* lhist = reinterpret_cast<int*>(smem);          // NBUCK ints
        int* lbase = lhist + NBUCK;                          // NBUCK ints (12.5 KB total)

        for (int i = t; i < NBUCK; i += 256) lhist[i] = 0;
        __syncthreads();

        int sv[BIN_EPT], dv[BIN_EPT];
        bool val[BIN_EPT];
#pragma unroll
        for (int i = 0; i < BIN_EPT; ++i) {
            int e = blockIdx.x * (256 * BIN_EPT) + i * 256 + t;
            val[i] = e < NE;
            sv[i] = 0; dv[i] = 0;
            if (val[i]) { sv[i] = src[e]; dv[i] = dst[e]; }
        }
#pragma unroll
        for (int i = 0; i < BIN_EPT; ++i)
            if (val[i]) atomicAdd(&lhist[dv[i] >> 6], 1);
        __syncthreads();

        for (int i = t; i < NBUCK; i += 256) {
            int c = lhist[i];
            lbase[i] = c ? atomicAdd(&bcnt[i], c) : 0;
            lhist[i] = 0;                  // reuse as local running rank
        }
        __syncthreads();

#pragma unroll
        for (int i = 0; i < BIN_EPT; ++i) {
            if (val[i]) {
                int b = dv[i] >> 6;
                int r = atomicAdd(&lhist[b], 1);               // LDS atomic
                coarse[b * CAPB + lbase[b] + r] =
                    ((unsigned int)sv[i] << 6) | (unsigned int)(dv[i] & 63);
            }
        }
        return;
    }

    // ---- zs branch: z = h@W (bf16), s_src, s_dst ----
    int base = (blockIdx.x - BIN_BLOCKS) * 64;

    const float4* hg = reinterpret_cast<const float4*>(h);
#pragma unroll
    for (int i = 0; i < 8; ++i) {
        int fidx = i * 256 + t;           // 0..2047
        int r = fidx >> 5;
        int c = fidx & 31;
        float4 v = make_float4(0.f, 0.f, 0.f, 0.f);
        if (base + r < NN) v = hg[(base + r) * 32 + c];
        smem[r * 33 + c] = v;
    }
    __syncthreads();

    int row = t & 63;
    int cg_ = t >> 6;
    int cgu = __builtin_amdgcn_readfirstlane(cg_);
    const float* Wc = W + cgu * 16;

    float acc[16];
#pragma unroll
    for (int j = 0; j < 16; ++j) acc[j] = 0.f;

#pragma unroll 8
    for (int k4 = 0; k4 < 32; ++k4) {
        float4 hv = smem[row * 33 + k4];
        const float* w = Wc + k4 * 4 * OUTD;
#pragma unroll
        for (int kk = 0; kk < 4; ++kk) {
            float hk = (&hv.x)[kk];
#pragma unroll
            for (int j = 0; j < 16; ++j)
                acc[j] = fmaf(hk, w[kk * OUTD + j], acc[j]);
        }
    }

    float s1 = 0.f, s2 = 0.f;
#pragma unroll
    for (int j = 0; j < 16; ++j) {
        s1 = fmaf(acc[j], a[cgu * 16 + j], s1);
        s2 = fmaf(acc[j], a[OUTD + cgu * 16 + j], s2);
    }

    __syncthreads();
    float* red = reinterpret_cast<float*>(smem);
    red[t] = s1;
    red[256 + t] = s2;
    __syncthreads();
    if (t < 64 && base + t < NN) {
        float t1 = red[t] + red[t + 64] + red[t + 128] + red[t + 192];
        float t2 = red[256 + t] + red[256 + t + 64] + red[256 + t + 128] + red[256 + t + 192];
        s_src[base + t] = t1;
        s_dst[base + t] = t2;
    }

    if (base + row < NN) {
        unsigned int u[8];
#pragma unroll
        for (int p = 0; p < 8; ++p) {
            unsigned int lo = f32_to_bf16_rne(acc[2 * p]);
            unsigned int hi = f32_to_bf16_rne(acc[2 * p + 1]);
            u[p] = lo | (hi << 16);
        }
        unsigned short* zp = z16 + (base + row) * OUTD + cgu * 16;
        uint4* z4 = reinterpret_cast<uint4*>(zp);
        z4[0] = make_uint4(u[0], u[1], u[2], u[3]);
        z4[1] = make_uint4(u[4], u[5], u[6], u[7]);
    }
}

// ---------------- pass 2: per-bucket LDS sub-CSR + softmax + aggregate ----------------
// Block = 512 threads (8 waves) handles 64 nodes: 8 nodes per wave.
// Aggregation layout: lane = (edge_slot<<4) | col_group; each wave-load fetches
// 4 z-rows (uint2 = 4 bf16 cols per lane).
__global__ void __launch_bounds__(512) k_node(
    const unsigned short* __restrict__ z16, const unsigned int* __restrict__ coarse,
    const int* __restrict__ bcnt, const float* __restrict__ s_src,
    const float* __restrict__ s_dst, float* __restrict__ out)
{
    __shared__ unsigned int seg[BK_NODES * CAPN];   // 16 KB
    __shared__ int cnt[BK_NODES];
    int b = blockIdx.x;
    int t = threadIdx.x;

    if (t < BK_NODES) cnt[t] = 0;
    __syncthreads();

    int nb = bcnt[b];
    if (nb > CAPB) nb = CAPB;
    const unsigned int* cb = coarse + b * CAPB;
    for (int i = t; i < nb; i += 512) {
        unsigned int v = cb[i];                     // coalesced
        int dl = (int)(v & 63u);
        int s  = (int)(v >> 6);
        int r = atomicAdd(&cnt[dl], 1);             // LDS atomic
        if (r < CAPN) seg[dl * CAPN + r] = s;
    }
    __syncthreads();

    int wave = t >> 6;      // 0..7
    int lane = t & 63;
    int eslot = lane >> 4;          // 0..3  (edge slot within 4-row load group)
    int cbase = (lane & 15) * 4;    // starting column (4 cols per lane)

    for (int ni = wave; ni < BK_NODES; ni += 8) {
        int node = b * BK_NODES + ni;
        if (node >= NN) continue;
        int d = cnt[ni];
        if (d > CAPN) d = CAPN;
        if (d == 0) {
            if (eslot == 0)
                *reinterpret_cast<float4*>(out + node * OUTD + cbase) =
                    make_float4(0.f, 0.f, 0.f, 0.f);
            continue;
        }
        float sdst = s_dst[node];

        // softmax phase: lane t owns edge t (d <= 64)
        int sid = 0;
        float ev = -INFINITY;
        if (lane < d) {
            sid = (int)seg[ni * CAPN + lane];        // LDS, stride-1
            float e0 = s_src[sid] + sdst;            // random 4B gather, cache-resident
            ev = e0 > 0.f ? e0 : 0.01f * e0;         // leaky_relu
        }
        int rowoff = sid * OUTD;

        float m = ev;
#pragma unroll
        for (int mm = 32; mm; mm >>= 1) m = fmaxf(m, __shfl_xor(m, mm, 64));
        float ex = (lane < d) ? __expf(ev - m) : 0.f;
        float l = ex;
#pragma unroll
        for (int mm = 32; mm; mm >>= 1) l += __shfl_xor(l, mm, 64);

        // aggregation: 4 edges per wave-load, uint2 (4 bf16 cols) per lane
        float a0 = 0.f, a1 = 0.f, a2 = 0.f, a3 = 0.f;
#pragma unroll 4
        for (int tt = 0; tt < d; tt += 4) {
            int e = tt + eslot;                      // < 64 always
            int ro = __shfl(rowoff, e, 64);          // bpermute
            float exv = __shfl(ex, e, 64);           // bpermute (0 if e >= d)
            uint2 v = *reinterpret_cast<const uint2*>(z16 + ro + cbase);
            float f0 = __uint_as_float(v.x << 16);
            float f1 = __uint_as_float(v.x & 0xFFFF0000u);
            float f2 = __uint_as_float(v.y << 16);
            float f3 = __uint_as_float(v.y & 0xFFFF0000u);
            a0 = fmaf(exv, f0, a0);
            a1 = fmaf(exv, f1, a1);
            a2 = fmaf(exv, f2, a2);
            a3 = fmaf(exv, f3, a3);
        }

        // reduce across the 4 edge slots (lanes ^16, ^32)
        a0 += __shfl_xor(a0, 16, 64); a0 += __shfl_xor(a0, 32, 64);
        a1 += __shfl_xor(a1, 16, 64); a1 += __shfl_xor(a1, 32, 64);
        a2 += __shfl_xor(a2, 16, 64); a2 += __shfl_xor(a2, 32, 64);
        a3 += __shfl_xor(a3, 16, 64); a3 += __shfl_xor(a3, 32, 64);

        if (eslot == 0) {                            // lanes 0..15: coalesced float4
            float inv = 1.f / l;
            *reinterpret_cast<float4*>(out + node * OUTD + cbase) =
                make_float4(a0 * inv, a1 * inv, a2 * inv, a3 * inv);
        }
    }
}

// ---------------- launcher ----------------
extern "C" void kernel_launch(void* const* d_in, const int* in_sizes, int n_in,
                              void* d_out, int out_size, void* d_ws, size_t ws_size,
                              hipStream_t stream)
{
    const float* h   = (const float*)d_in[0];
    const float* W   = (const float*)d_in[1];
    const float* a   = (const float*)d_in[2];
    const int*   src = (const int*)d_in[3];
    const int*   dst = (const int*)d_in[4];
    float* out = (float*)d_out;

    int* ws_i = (int*)d_ws;

    unsigned short* z16 = (unsigned short*)(ws_i + OFF_Z);
    float* s_src  = (float*)(ws_i + OFF_SSRC);
    float* s_dst  = (float*)(ws_i + OFF_SDST);
    int*   bcnt   = ws_i + OFF_BCNT;
    unsigned int* coarse = (unsigned int*)(ws_i + OFF_COARSE);

    hipMemsetAsync(bcnt, 0, NBUCK * sizeof(int), stream);

    // merged pre-pass: bin blocks [0,782) + zs blocks [782,2345)
    k_pre<<<PRE_BLOCKS, 256, 0, stream>>>(h, W, a, src, dst, z16, s_src, s_dst,
                                          bcnt, coarse);

    // per-bucket LDS sub-CSR + softmax + aggregation (8 waves/block, 64 nodes)
    k_node<<<NBUCK, 512, 0, stream>>>(z16, coarse, bcnt, s_src, s_dst, out);
}

// Round 12
// 129.585 us; speedup vs baseline: 1.0825x; 1.0825x over previous
//
#include <hip/hip_runtime.h>
#include <math.h>

#define NN   100000
#define NE   1600000
#define IND  128
#define OUTD 64

#define BK_NODES 64                      // nodes per bucket
#define NBUCK    1563                    // ceil(NN / 64); 1563*64 = 100032
#define CAPB     1280                    // edge capacity per bucket (mean 1024, +8 sigma)
#define CAPN     64                      // per-node slots in LDS (P(deg>64)~1e-14, Poisson(16))

// ---------------- ws layout (4-byte words) ----------------
#define OFF_Z      0                          // NN*OUTD bf16 = NN*32 words
#define OFF_SSRC   (OFF_Z + NN * OUTD / 2)    // NN f32
#define OFF_SDST   (OFF_SSRC + NN)            // NN f32
#define OFF_BCNT   (OFF_SDST + NN)            // NBUCK i32
#define OFF_COARSE (OFF_BCNT + NBUCK)         // NBUCK*CAPB u32 packed (src<<6 | dstLocal)
// total ~= 22 MB

__device__ __forceinline__ unsigned short f32_to_bf16_rne(float x)
{
    unsigned int b = __float_as_uint(x);
    b += 0x7FFFu + ((b >> 16) & 1u);
    return (unsigned short)(b >> 16);
}

// ---------------- z = h@W (bf16 out), s_src = z.a_src, s_dst = z.a_dst ----------------
__global__ void __launch_bounds__(256) k_zs(
    const float* __restrict__ h, const float* __restrict__ W,
    const float* __restrict__ a, unsigned short* __restrict__ z16,
    float* __restrict__ s_src, float* __restrict__ s_dst)
{
    __shared__ float4 tile[64 * 33];      // 64 rows, 32 float4 + 1 pad
    int tid = threadIdx.x;
    int base = blockIdx.x * 64;

    const float4* hg = reinterpret_cast<const float4*>(h);
#pragma unroll
    for (int i = 0; i < 8; ++i) {
        int fidx = i * 256 + tid;         // 0..2047
        int r = fidx >> 5;
        int c = fidx & 31;
        float4 v = make_float4(0.f, 0.f, 0.f, 0.f);
        if (base + r < NN) v = hg[(base + r) * 32 + c];
        tile[r * 33 + c] = v;
    }
    __syncthreads();

    int row = tid & 63;
    int cg_ = tid >> 6;
    int cgu = __builtin_amdgcn_readfirstlane(cg_);
    const float* Wc = W + cgu * 16;

    float acc[16];
#pragma unroll
    for (int j = 0; j < 16; ++j) acc[j] = 0.f;

#pragma unroll 8
    for (int k4 = 0; k4 < 32; ++k4) {
        float4 hv = tile[row * 33 + k4];
        const float* w = Wc + k4 * 4 * OUTD;
#pragma unroll
        for (int kk = 0; kk < 4; ++kk) {
            float hk = (&hv.x)[kk];
#pragma unroll
            for (int j = 0; j < 16; ++j)
                acc[j] = fmaf(hk, w[kk * OUTD + j], acc[j]);
        }
    }

    float s1 = 0.f, s2 = 0.f;
#pragma unroll
    for (int j = 0; j < 16; ++j) {
        s1 = fmaf(acc[j], a[cgu * 16 + j], s1);
        s2 = fmaf(acc[j], a[OUTD + cgu * 16 + j], s2);
    }

    __syncthreads();
    float* red = reinterpret_cast<float*>(tile);
    red[tid] = s1;
    red[256 + tid] = s2;
    __syncthreads();
    if (tid < 64 && base + tid < NN) {
        float t1 = red[tid] + red[tid + 64] + red[tid + 128] + red[tid + 192];
        float t2 = red[256 + tid] + red[256 + tid + 64] + red[256 + tid + 128] + red[256 + tid + 192];
        s_src[base + tid] = t1;
        s_dst[base + tid] = t2;
    }

    // store bf16 z slice: 16 cols -> 8 packed uints -> 2 uint4 stores
    if (base + row < NN) {
        unsigned int u[8];
#pragma unroll
        for (int p = 0; p < 8; ++p) {
            unsigned int lo = f32_to_bf16_rne(acc[2 * p]);
            unsigned int hi = f32_to_bf16_rne(acc[2 * p + 1]);
            u[p] = lo | (hi << 16);
        }
        unsigned short* zp = z16 + (base + row) * OUTD + cgu * 16;
        uint4* z4 = reinterpret_cast<uint4*>(zp);
        z4[0] = make_uint4(u[0], u[1], u[2], u[3]);
        z4[1] = make_uint4(u[4], u[5], u[6], u[7]);
    }
}

// ---------------- pass 1: bin edges by 64-node bucket ----------------
#define BIN_THREADS 1024
#define BIN_EPT     4
#define BIN_BLOCKS  391   // 391*1024*4 = 1,601,536 >= NE

__global__ void __launch_bounds__(BIN_THREADS) k_bin(
    const int* __restrict__ src, const int* __restrict__ dst,
    int* __restrict__ bcnt, unsigned int* __restrict__ coarse)
{
    __shared__ int lhist[NBUCK];
    __shared__ int lbase[NBUCK];
    int t = threadIdx.x;

    for (int i = t; i < NBUCK; i += BIN_THREADS) lhist[i] = 0;
    __syncthreads();

    int sv[BIN_EPT], dv[BIN_EPT];
    bool val[BIN_EPT];
#pragma unroll
    for (int i = 0; i < BIN_EPT; ++i) {
        int e = blockIdx.x * (BIN_THREADS * BIN_EPT) + i * BIN_THREADS + t;
        val[i] = e < NE;
        sv[i] = 0; dv[i] = 0;
        if (val[i]) { sv[i] = src[e]; dv[i] = dst[e]; }
    }
#pragma unroll
    for (int i = 0; i < BIN_EPT; ++i)
        if (val[i]) atomicAdd(&lhist[dv[i] >> 6], 1);
    __syncthreads();

    // reserve global ranges: one global atomic per nonzero bucket counter
    for (int i = t; i < NBUCK; i += BIN_THREADS) {
        int c = lhist[i];
        lbase[i] = c ? atomicAdd(&bcnt[i], c) : 0;
        lhist[i] = 0;                      // reuse as local running rank
    }
    __syncthreads();

    // scatter packed entries into reserved ranges
#pragma unroll
    for (int i = 0; i < BIN_EPT; ++i) {
        if (val[i]) {
            int b = dv[i] >> 6;
            int r = atomicAdd(&lhist[b], 1);           // LDS atomic
            coarse[b * CAPB + lbase[b] + r] =
                ((unsigned int)sv[i] << 6) | (unsigned int)(dv[i] & 63);
        }
    }
}

// ---------------- pass 2: per-bucket LDS sub-CSR + softmax + aggregate ----------------
// Block = 512 threads (8 waves) handles 64 nodes: 8 nodes per wave.
// Aggregation layout: lane = (edge_slot<<4) | col_group; each wave-load fetches
// 4 z-rows (uint2 = 4 bf16 cols per lane).
__global__ void __launch_bounds__(512) k_node(
    const unsigned short* __restrict__ z16, const unsigned int* __restrict__ coarse,
    const int* __restrict__ bcnt, const float* __restrict__ s_src,
    const float* __restrict__ s_dst, float* __restrict__ out)
{
    __shared__ unsigned int seg[BK_NODES * CAPN];   // 16 KB
    __shared__ int cnt[BK_NODES];
    int b = blockIdx.x;
    int t = threadIdx.x;

    if (t < BK_NODES) cnt[t] = 0;
    __syncthreads();

    int nb = bcnt[b];
    if (nb > CAPB) nb = CAPB;
    const unsigned int* cb = coarse + b * CAPB;
    for (int i = t; i < nb; i += 512) {
        unsigned int v = cb[i];                     // coalesced
        int dl = (int)(v & 63u);
        int s  = (int)(v >> 6);
        int r = atomicAdd(&cnt[dl], 1);             // LDS atomic
        if (r < CAPN) seg[dl * CAPN + r] = s;
    }
    __syncthreads();

    int wave = t >> 6;      // 0..7
    int lane = t & 63;
    int eslot = lane >> 4;          // 0..3  (edge slot within 4-row load group)
    int cbase = (lane & 15) * 4;    // starting column (4 cols per lane)

    for (int ni = wave; ni < BK_NODES; ni += 8) {
        int node = b * BK_NODES + ni;
        if (node >= NN) continue;
        int d = cnt[ni];
        if (d > CAPN) d = CAPN;
        if (d == 0) {
            if (eslot == 0)
                *reinterpret_cast<float4*>(out + node * OUTD + cbase) =
                    make_float4(0.f, 0.f, 0.f, 0.f);
            continue;
        }
        float sdst = s_dst[node];

        // softmax phase: lane t owns edge t (d <= 64)
        int sid = 0;
        float ev = -INFINITY;
        if (lane < d) {
            sid = (int)seg[ni * CAPN + lane];        // LDS, stride-1
            float e0 = s_src[sid] + sdst;            // random 4B gather, cache-resident
            ev = e0 > 0.f ? e0 : 0.01f * e0;         // leaky_relu
        }
        int rowoff = sid * OUTD;

        float m = ev;
#pragma unroll
        for (int mm = 32; mm; mm >>= 1) m = fmaxf(m, __shfl_xor(m, mm, 64));
        float ex = (lane < d) ? __expf(ev - m) : 0.f;
        float l = ex;
#pragma unroll
        for (int mm = 32; mm; mm >>= 1) l += __shfl_xor(l, mm, 64);

        // aggregation: 4 edges per wave-load, uint2 (4 bf16 cols) per lane
        float a0 = 0.f, a1 = 0.f, a2 = 0.f, a3 = 0.f;
#pragma unroll 4
        for (int tt = 0; tt < d; tt += 4) {
            int e = tt + eslot;                      // < 64 always
            int ro = __shfl(rowoff, e, 64);          // bpermute
            float exv = __shfl(ex, e, 64);           // bpermute (0 if e >= d)
            uint2 v = *reinterpret_cast<const uint2*>(z16 + ro + cbase);
            float f0 = __uint_as_float(v.x << 16);
            float f1 = __uint_as_float(v.x & 0xFFFF0000u);
            float f2 = __uint_as_float(v.y << 16);
            float f3 = __uint_as_float(v.y & 0xFFFF0000u);
            a0 = fmaf(exv, f0, a0);
            a1 = fmaf(exv, f1, a1);
            a2 = fmaf(exv, f2, a2);
            a3 = fmaf(exv, f3, a3);
        }

        // reduce across the 4 edge slots (lanes ^16, ^32)
        a0 += __shfl_xor(a0, 16, 64); a0 += __shfl_xor(a0, 32, 64);
        a1 += __shfl_xor(a1, 16, 64); a1 += __shfl_xor(a1, 32, 64);
        a2 += __shfl_xor(a2, 16, 64); a2 += __shfl_xor(a2, 32, 64);
        a3 += __shfl_xor(a3, 16, 64); a3 += __shfl_xor(a3, 32, 64);

        if (eslot == 0) {                            // lanes 0..15: coalesced float4
            float inv = 1.f / l;
            *reinterpret_cast<float4*>(out + node * OUTD + cbase) =
                make_float4(a0 * inv, a1 * inv, a2 * inv, a3 * inv);
        }
    }
}

// ---------------- launcher ----------------
extern "C" void kernel_launch(void* const* d_in, const int* in_sizes, int n_in,
                              void* d_out, int out_size, void* d_ws, size_t ws_size,
                              hipStream_t stream)
{
    const float* h   = (const float*)d_in[0];
    const float* W   = (const float*)d_in[1];
    const float* a   = (const float*)d_in[2];
    const int*   src = (const int*)d_in[3];
    const int*   dst = (const int*)d_in[4];
    float* out = (float*)d_out;

    int* ws_i = (int*)d_ws;

    unsigned short* z16 = (unsigned short*)(ws_i + OFF_Z);
    float* s_src  = (float*)(ws_i + OFF_SSRC);
    float* s_dst  = (float*)(ws_i + OFF_SDST);
    int*   bcnt   = ws_i + OFF_BCNT;
    unsigned int* coarse = (unsigned int*)(ws_i + OFF_COARSE);

    hipMemsetAsync(bcnt, 0, NBUCK * sizeof(int), stream);

    // bin edges by 64-node bucket (separate kernels — merge regressed in R11)
    k_bin<<<BIN_BLOCKS, BIN_THREADS, 0, stream>>>(src, dst, bcnt, coarse);

    // z (bf16), s_src, s_dst
    k_zs<<<(NN + 63) / 64, 256, 0, stream>>>(h, W, a, z16, s_src, s_dst);

    // per-bucket LDS sub-CSR + softmax + aggregation (8 waves/block, 64 nodes)
    k_node<<<NBUCK, 512, 0, stream>>>(z16, coarse, bcnt, s_src, s_dst, out);
}

// Round 13
// 121.396 us; speedup vs baseline: 1.1555x; 1.0675x over previous
//
#include <hip/hip_runtime.h>
#include <math.h>

#define NN   100000
#define NE   1600000
#define IND  128
#define OUTD 64

#define BK_NODES 64                      // nodes per bucket
#define NBUCK    1563                    // ceil(NN / 64); 1563*64 = 100032
#define CAPB     1280                    // edge capacity per bucket (mean 1024, +8 sigma)
#define CAPN     64                      // per-node slots in LDS

// ---------------- ws layout (4-byte words) ----------------
#define OFF_Z      0                          // NN*OUTD bf16 = NN*32 words
#define OFF_SSRC   (OFF_Z + NN * OUTD / 2)    // NN f32
#define OFF_SDST   (OFF_SSRC + NN)            // NN f32
#define OFF_BCNT   (OFF_SDST + NN)            // NBUCK i32
#define OFF_TICKET (OFF_BCNT + NBUCK)         // 1 i32 (dynamic bucket scheduler)
#define OFF_COARSE (OFF_TICKET + 1)           // NBUCK*CAPB u32 packed (src<<6 | dstLocal)
// total ~= 22 MB

typedef __bf16 bf16x8 __attribute__((ext_vector_type(8)));
typedef unsigned short u16x8 __attribute__((ext_vector_type(8)));
typedef float f32x4 __attribute__((ext_vector_type(4)));

union FragU { u16x8 u; bf16x8 b; };

__device__ __forceinline__ unsigned short f32_to_bf16_rne(float x)
{
    unsigned int b = __float_as_uint(x);
    b += 0x7FFFu + ((b >> 16) & 1u);
    return (unsigned short)(b >> 16);
}

// ---------------- z = h@W via MFMA (bf16), s_src, s_dst ----------------
// Block = 256 thr (4 waves). W staged once in LDS as bf16 [64 cols][136 k-pad];
// each lane pre-loads all 16 B-frags; each wave computes one 16-row tile.
#define WLPAD 136     // 128 k + 8 pad (keeps 16B alignment: 136 % 8 == 0)

__global__ void __launch_bounds__(256) k_zs(
    const float* __restrict__ h, const float* __restrict__ W,
    const float* __restrict__ a, unsigned short* __restrict__ z16,
    float* __restrict__ s_src, float* __restrict__ s_dst)
{
    __shared__ __attribute__((aligned(16))) unsigned short WL[OUTD * WLPAD]; // 17.4 KB
    int t = threadIdx.x;

    // stage W (128x64 f32, row-major) -> WL[col][k] bf16
    for (int idx = t; idx < IND * OUTD; idx += 256) {
        int k = idx >> 6;            // 0..127   (coalesced global read: c fast)
        int c = idx & 63;
        WL[c * WLPAD + k] = f32_to_bf16_rne(W[idx]);
    }
    __syncthreads();

    int lane = t & 63;
    int wave = t >> 6;
    int c = lane & 15;               // 16-dim index (A-row / B-col / C-col)
    int g = lane >> 4;               // k-group 0..3

    // pre-load all B fragments: b[ks][nt], lane elem j = W[ks*32+g*8+j][nt*16+c]
    FragU bf[4][4];
#pragma unroll
    for (int ks = 0; ks < 4; ++ks)
#pragma unroll
        for (int nt = 0; nt < 4; ++nt)
            bf[ks][nt].u = *reinterpret_cast<const u16x8*>(
                &WL[(nt * 16 + c) * WLPAD + ks * 32 + g * 8]);

    // A rows for this wave
    int rbase = blockIdx.x * 64 + wave * 16;
    int rowA = rbase + c;
    int rowAc = rowA < NN ? rowA : NN - 1;       // clamp (stores are guarded)
    const float* hrow = h + rowAc * IND;

    FragU af[4];
#pragma unroll
    for (int ks = 0; ks < 4; ++ks) {
        float4 p = *reinterpret_cast<const float4*>(hrow + ks * 32 + g * 8);
        float4 q = *reinterpret_cast<const float4*>(hrow + ks * 32 + g * 8 + 4);
        u16x8 u;
        u[0] = f32_to_bf16_rne(p.x); u[1] = f32_to_bf16_rne(p.y);
        u[2] = f32_to_bf16_rne(p.z); u[3] = f32_to_bf16_rne(p.w);
        u[4] = f32_to_bf16_rne(q.x); u[5] = f32_to_bf16_rne(q.y);
        u[6] = f32_to_bf16_rne(q.z); u[7] = f32_to_bf16_rne(q.w);
        af[ks].u = u;
    }

    f32x4 acc[4];
#pragma unroll
    for (int nt = 0; nt < 4; ++nt) acc[nt] = (f32x4){0.f, 0.f, 0.f, 0.f};

#pragma unroll
    for (int nt = 0; nt < 4; ++nt)
#pragma unroll
        for (int ks = 0; ks < 4; ++ks)
            acc[nt] = __builtin_amdgcn_mfma_f32_16x16x32_bf16(
                af[ks].b, bf[ks][nt].b, acc[nt], 0, 0, 0);

    // epilogue: C/D layout col = c, row = g*4 + reg
    float as[4], ad[4];
#pragma unroll
    for (int nt = 0; nt < 4; ++nt) {
        as[nt] = a[nt * 16 + c];
        ad[nt] = a[OUTD + nt * 16 + c];
    }

#pragma unroll
    for (int reg = 0; reg < 4; ++reg) {
        int row = rbase + g * 4 + reg;
        float p1 = 0.f, p2 = 0.f;
#pragma unroll
        for (int nt = 0; nt < 4; ++nt) {
            float v = acc[nt][reg];
            p1 = fmaf(v, as[nt], p1);
            p2 = fmaf(v, ad[nt], p2);
            if (row < NN)
                z16[row * OUTD + nt * 16 + c] = f32_to_bf16_rne(v);
        }
        // reduce over the 16 c-lanes (stay within 16-lane group)
#pragma unroll
        for (int mm = 1; mm < 16; mm <<= 1) {
            p1 += __shfl_xor(p1, mm, 64);
            p2 += __shfl_xor(p2, mm, 64);
        }
        if (c == 0 && row < NN) {
            s_src[row] = p1;
            s_dst[row] = p2;
        }
    }
}

// ---------------- pass 1: bin edges by 64-node bucket ----------------
#define BIN_THREADS 1024
#define BIN_EPT     4
#define BIN_BLOCKS  391   // 391*1024*4 = 1,601,536 >= NE

__global__ void __launch_bounds__(BIN_THREADS) k_bin(
    const int* __restrict__ src, const int* __restrict__ dst,
    int* __restrict__ bcnt, unsigned int* __restrict__ coarse)
{
    __shared__ int lhist[NBUCK];
    __shared__ int lbase[NBUCK];
    int t = threadIdx.x;

    for (int i = t; i < NBUCK; i += BIN_THREADS) lhist[i] = 0;
    __syncthreads();

    int sv[BIN_EPT], dv[BIN_EPT];
    bool val[BIN_EPT];
#pragma unroll
    for (int i = 0; i < BIN_EPT; ++i) {
        int e = blockIdx.x * (BIN_THREADS * BIN_EPT) + i * BIN_THREADS + t;
        val[i] = e < NE;
        sv[i] = 0; dv[i] = 0;
        if (val[i]) { sv[i] = src[e]; dv[i] = dst[e]; }
    }
#pragma unroll
    for (int i = 0; i < BIN_EPT; ++i)
        if (val[i]) atomicAdd(&lhist[dv[i] >> 6], 1);
    __syncthreads();

    for (int i = t; i < NBUCK; i += BIN_THREADS) {
        int c = lhist[i];
        lbase[i] = c ? atomicAdd(&bcnt[i], c) : 0;
        lhist[i] = 0;                      // reuse as local running rank
    }
    __syncthreads();

#pragma unroll
    for (int i = 0; i < BIN_EPT; ++i) {
        if (val[i]) {
            int b = dv[i] >> 6;
            int r = atomicAdd(&lhist[b], 1);           // LDS atomic
            coarse[b * CAPB + lbase[b] + r] =
                ((unsigned int)sv[i] << 6) | (unsigned int)(dv[i] & 63);
        }
    }
}

// ---------------- pass 2: per-bucket LDS sub-CSR + softmax + aggregate ----------------
// Persistent blocks (512 thr, 8 waves) pull bucket ids from a global ticket.
__global__ void __launch_bounds__(512) k_node(
    const unsigned short* __restrict__ z16, const unsigned int* __restrict__ coarse,
    const int* __restrict__ bcnt, const float* __restrict__ s_src,
    const float* __restrict__ s_dst, int* __restrict__ ticket,
    float* __restrict__ out)
{
    __shared__ unsigned int seg[BK_NODES * CAPN];   // 16 KB
    __shared__ int cnt[BK_NODES];
    __shared__ int sh_b;
    int t = threadIdx.x;

    int wave = t >> 6;      // 0..7
    int lane = t & 63;
    int eslot = lane >> 4;          // 0..3
    int cbase = (lane & 15) * 4;

    for (;;) {
        if (t == 0) sh_b = atomicAdd(ticket, 1);
        __syncthreads();                // also fences previous iteration's readers
        int b = sh_b;
        if (b >= NBUCK) return;

        if (t < BK_NODES) cnt[t] = 0;
        __syncthreads();

        int nb = bcnt[b];
        if (nb > CAPB) nb = CAPB;
        const unsigned int* cb = coarse + b * CAPB;
        for (int i = t; i < nb; i += 512) {
            unsigned int v = cb[i];                     // coalesced
            int dl = (int)(v & 63u);
            int s  = (int)(v >> 6);
            int r = atomicAdd(&cnt[dl], 1);             // LDS atomic
            if (r < CAPN) seg[dl * CAPN + r] = s;
        }
        __syncthreads();

        for (int ni = wave; ni < BK_NODES; ni += 8) {
            int node = b * BK_NODES + ni;
            if (node >= NN) continue;
            int d = cnt[ni];
            if (d > CAPN) d = CAPN;
            if (d == 0) {
                if (eslot == 0)
                    *reinterpret_cast<float4*>(out + node * OUTD + cbase) =
                        make_float4(0.f, 0.f, 0.f, 0.f);
                continue;
            }
            float sdst = s_dst[node];

            int sid = 0;
            float ev = -INFINITY;
            if (lane < d) {
                sid = (int)seg[ni * CAPN + lane];        // LDS, stride-1
                float e0 = s_src[sid] + sdst;            // random 4B gather
                ev = e0 > 0.f ? e0 : 0.01f * e0;         // leaky_relu
            }
            int rowoff = sid * OUTD;

            float m = ev;
#pragma unroll
            for (int mm = 32; mm; mm >>= 1) m = fmaxf(m, __shfl_xor(m, mm, 64));
            float ex = (lane < d) ? __expf(ev - m) : 0.f;
            float l = ex;
#pragma unroll
            for (int mm = 32; mm; mm >>= 1) l += __shfl_xor(l, mm, 64);

            // aggregation: 4 edges per wave-load, uint2 (4 bf16 cols) per lane
            float a0 = 0.f, a1 = 0.f, a2 = 0.f, a3 = 0.f;
#pragma unroll 4
            for (int tt = 0; tt < d; tt += 4) {
                int e = tt + eslot;
                int ro = __shfl(rowoff, e, 64);
                float exv = __shfl(ex, e, 64);           // 0 if e >= d
                uint2 v = *reinterpret_cast<const uint2*>(z16 + ro + cbase);
                float f0 = __uint_as_float(v.x << 16);
                float f1 = __uint_as_float(v.x & 0xFFFF0000u);
                float f2 = __uint_as_float(v.y << 16);
                float f3 = __uint_as_float(v.y & 0xFFFF0000u);
                a0 = fmaf(exv, f0, a0);
                a1 = fmaf(exv, f1, a1);
                a2 = fmaf(exv, f2, a2);
                a3 = fmaf(exv, f3, a3);
            }

            a0 += __shfl_xor(a0, 16, 64); a0 += __shfl_xor(a0, 32, 64);
            a1 += __shfl_xor(a1, 16, 64); a1 += __shfl_xor(a1, 32, 64);
            a2 += __shfl_xor(a2, 16, 64); a2 += __shfl_xor(a2, 32, 64);
            a3 += __shfl_xor(a3, 16, 64); a3 += __shfl_xor(a3, 32, 64);

            if (eslot == 0) {
                float inv = 1.f / l;
                *reinterpret_cast<float4*>(out + node * OUTD + cbase) =
                    make_float4(a0 * inv, a1 * inv, a2 * inv, a3 * inv);
            }
        }
    }
}

// ---------------- launcher ----------------
extern "C" void kernel_launch(void* const* d_in, const int* in_sizes, int n_in,
                              void* d_out, int out_size, void* d_ws, size_t ws_size,
                              hipStream_t stream)
{
    const float* h   = (const float*)d_in[0];
    const float* W   = (const float*)d_in[1];
    const float* a   = (const float*)d_in[2];
    const int*   src = (const int*)d_in[3];
    const int*   dst = (const int*)d_in[4];
    float* out = (float*)d_out;

    int* ws_i = (int*)d_ws;

    unsigned short* z16 = (unsigned short*)(ws_i + OFF_Z);
    float* s_src  = (float*)(ws_i + OFF_SSRC);
    float* s_dst  = (float*)(ws_i + OFF_SDST);
    int*   bcnt   = ws_i + OFF_BCNT;
    int*   ticket = ws_i + OFF_TICKET;
    unsigned int* coarse = (unsigned int*)(ws_i + OFF_COARSE);

    hipMemsetAsync(bcnt, 0, (NBUCK + 1) * sizeof(int), stream);   // bcnt + ticket

    // bin edges by 64-node bucket
    k_bin<<<BIN_BLOCKS, BIN_THREADS, 0, stream>>>(src, dst, bcnt, coarse);

    // z (bf16) via MFMA, s_src, s_dst
    k_zs<<<(NN + 63) / 64, 256, 0, stream>>>(h, W, a, z16, s_src, s_dst);

    // per-bucket LDS sub-CSR + softmax + aggregation (persistent, ticket-fed)
    k_node<<<1024, 512, 0, stream>>>(z16, coarse, bcnt, s_src, s_dst, ticket, out);
}

// Round 14
// 106.104 us; speedup vs baseline: 1.3221x; 1.1441x over previous
//
#include <hip/hip_runtime.h>
#include <math.h>

#define NN   100000
#define NE   1600000
#define IND  128
#define OUTD 64

#define BK_NODES 64                      // nodes per bucket
#define NBUCK    1563                    // ceil(NN / 64); 1563*64 = 100032
#define CAPB     1280                    // edge capacity per bucket (mean 1024, +8 sigma)
#define CAPN     64                      // per-node slots in LDS

// ---------------- ws layout (4-byte words) ----------------
#define OFF_Z      0                          // NN*OUTD bf16 = NN*32 words
#define OFF_SSRC   (OFF_Z + NN * OUTD / 2)    // NN f32
#define OFF_SDST   (OFF_SSRC + NN)            // NN f32
#define OFF_BCNT   (OFF_SDST + NN)            // NBUCK i32
#define OFF_COARSE (OFF_BCNT + NBUCK)         // NBUCK*CAPB u32 packed (src<<6 | dstLocal)
// total ~= 22 MB

typedef __bf16 bf16x8 __attribute__((ext_vector_type(8)));
typedef unsigned short u16x8 __attribute__((ext_vector_type(8)));
typedef float f32x4 __attribute__((ext_vector_type(4)));

union FragU { u16x8 u; bf16x8 b; };

__device__ __forceinline__ unsigned short f32_to_bf16_rne(float x)
{
    unsigned int b = __float_as_uint(x);
    b += 0x7FFFu + ((b >> 16) & 1u);
    return (unsigned short)(b >> 16);
}

// ---------------- z = h@W via MFMA (bf16), s_src, s_dst ----------------
// Block = 256 thr (4 waves). W staged once in LDS as bf16 [64 cols][136 k-pad];
// each lane pre-loads all 16 B-frags; each wave computes one 16-row tile.
#define WLPAD 136     // 128 k + 8 pad (keeps 16B alignment: 136 % 8 == 0)

__global__ void __launch_bounds__(256) k_zs(
    const float* __restrict__ h, const float* __restrict__ W,
    const float* __restrict__ a, unsigned short* __restrict__ z16,
    float* __restrict__ s_src, float* __restrict__ s_dst)
{
    __shared__ __attribute__((aligned(16))) unsigned short WL[OUTD * WLPAD]; // 17.4 KB
    int t = threadIdx.x;

    // stage W (128x64 f32, row-major) -> WL[col][k] bf16
    for (int idx = t; idx < IND * OUTD; idx += 256) {
        int k = idx >> 6;            // 0..127   (coalesced global read: c fast)
        int c = idx & 63;
        WL[c * WLPAD + k] = f32_to_bf16_rne(W[idx]);
    }
    __syncthreads();

    int lane = t & 63;
    int wave = t >> 6;
    int c = lane & 15;               // 16-dim index (A-row / B-col / C-col)
    int g = lane >> 4;               // k-group 0..3

    // pre-load all B fragments: b[ks][nt], lane elem j = W[ks*32+g*8+j][nt*16+c]
    FragU bf[4][4];
#pragma unroll
    for (int ks = 0; ks < 4; ++ks)
#pragma unroll
        for (int nt = 0; nt < 4; ++nt)
            bf[ks][nt].u = *reinterpret_cast<const u16x8*>(
                &WL[(nt * 16 + c) * WLPAD + ks * 32 + g * 8]);

    // A rows for this wave
    int rbase = blockIdx.x * 64 + wave * 16;
    int rowA = rbase + c;
    int rowAc = rowA < NN ? rowA : NN - 1;       // clamp (stores are guarded)
    const float* hrow = h + rowAc * IND;

    FragU af[4];
#pragma unroll
    for (int ks = 0; ks < 4; ++ks) {
        float4 p = *reinterpret_cast<const float4*>(hrow + ks * 32 + g * 8);
        float4 q = *reinterpret_cast<const float4*>(hrow + ks * 32 + g * 8 + 4);
        u16x8 u;
        u[0] = f32_to_bf16_rne(p.x); u[1] = f32_to_bf16_rne(p.y);
        u[2] = f32_to_bf16_rne(p.z); u[3] = f32_to_bf16_rne(p.w);
        u[4] = f32_to_bf16_rne(q.x); u[5] = f32_to_bf16_rne(q.y);
        u[6] = f32_to_bf16_rne(q.z); u[7] = f32_to_bf16_rne(q.w);
        af[ks].u = u;
    }

    f32x4 acc[4];
#pragma unroll
    for (int nt = 0; nt < 4; ++nt) acc[nt] = (f32x4){0.f, 0.f, 0.f, 0.f};

#pragma unroll
    for (int nt = 0; nt < 4; ++nt)
#pragma unroll
        for (int ks = 0; ks < 4; ++ks)
            acc[nt] = __builtin_amdgcn_mfma_f32_16x16x32_bf16(
                af[ks].b, bf[ks][nt].b, acc[nt], 0, 0, 0);

    // epilogue: C/D layout col = c, row = g*4 + reg
    float as[4], ad[4];
#pragma unroll
    for (int nt = 0; nt < 4; ++nt) {
        as[nt] = a[nt * 16 + c];
        ad[nt] = a[OUTD + nt * 16 + c];
    }

#pragma unroll
    for (int reg = 0; reg < 4; ++reg) {
        int row = rbase + g * 4 + reg;
        float p1 = 0.f, p2 = 0.f;
#pragma unroll
        for (int nt = 0; nt < 4; ++nt) {
            float v = acc[nt][reg];
            p1 = fmaf(v, as[nt], p1);
            p2 = fmaf(v, ad[nt], p2);
            if (row < NN)
                z16[row * OUTD + nt * 16 + c] = f32_to_bf16_rne(v);
        }
        // reduce over the 16 c-lanes (stay within 16-lane group)
#pragma unroll
        for (int mm = 1; mm < 16; mm <<= 1) {
            p1 += __shfl_xor(p1, mm, 64);
            p2 += __shfl_xor(p2, mm, 64);
        }
        if (c == 0 && row < NN) {
            s_src[row] = p1;
            s_dst[row] = p2;
        }
    }
}

// ---------------- pass 1: bin edges by 64-node bucket ----------------
#define BIN_THREADS 1024
#define BIN_EPT     4
#define BIN_BLOCKS  391   // 391*1024*4 = 1,601,536 >= NE

__global__ void __launch_bounds__(BIN_THREADS) k_bin(
    const int* __restrict__ src, const int* __restrict__ dst,
    int* __restrict__ bcnt, unsigned int* __restrict__ coarse)
{
    __shared__ int lhist[NBUCK];
    __shared__ int lbase[NBUCK];
    int t = threadIdx.x;

    for (int i = t; i < NBUCK; i += BIN_THREADS) lhist[i] = 0;
    __syncthreads();

    int sv[BIN_EPT], dv[BIN_EPT];
    bool val[BIN_EPT];
#pragma unroll
    for (int i = 0; i < BIN_EPT; ++i) {
        int e = blockIdx.x * (BIN_THREADS * BIN_EPT) + i * BIN_THREADS + t;
        val[i] = e < NE;
        sv[i] = 0; dv[i] = 0;
        if (val[i]) { sv[i] = src[e]; dv[i] = dst[e]; }
    }
#pragma unroll
    for (int i = 0; i < BIN_EPT; ++i)
        if (val[i]) atomicAdd(&lhist[dv[i] >> 6], 1);
    __syncthreads();

    // reserve global ranges: one global atomic per nonzero bucket counter
    for (int i = t; i < NBUCK; i += BIN_THREADS) {
        int c = lhist[i];
        lbase[i] = c ? atomicAdd(&bcnt[i], c) : 0;
        lhist[i] = 0;                      // reuse as local running rank
    }
    __syncthreads();

    // scatter packed entries into reserved ranges
#pragma unroll
    for (int i = 0; i < BIN_EPT; ++i) {
        if (val[i]) {
            int b = dv[i] >> 6;
            int r = atomicAdd(&lhist[b], 1);           // LDS atomic
            coarse[b * CAPB + lbase[b] + r] =
                ((unsigned int)sv[i] << 6) | (unsigned int)(dv[i] & 63);
        }
    }
}

// ---------------- pass 2: per-bucket LDS sub-CSR + softmax + aggregate ----------------
// Static grid (cross-block phase overlap beats persistent ticket — R13 lesson).
// Block = 512 threads (8 waves) handles 64 nodes: 8 nodes per wave.
__global__ void __launch_bounds__(512) k_node(
    const unsigned short* __restrict__ z16, const unsigned int* __restrict__ coarse,
    const int* __restrict__ bcnt, const float* __restrict__ s_src,
    const float* __restrict__ s_dst, float* __restrict__ out)
{
    __shared__ unsigned int seg[BK_NODES * CAPN];   // 16 KB
    __shared__ int cnt[BK_NODES];
    int b = blockIdx.x;
    int t = threadIdx.x;

    if (t < BK_NODES) cnt[t] = 0;
    __syncthreads();

    int nb = bcnt[b];
    if (nb > CAPB) nb = CAPB;
    const unsigned int* cb = coarse + b * CAPB;
    for (int i = t; i < nb; i += 512) {
        unsigned int v = cb[i];                     // coalesced
        int dl = (int)(v & 63u);
        int s  = (int)(v >> 6);
        int r = atomicAdd(&cnt[dl], 1);             // LDS atomic
        if (r < CAPN) seg[dl * CAPN + r] = s;
    }
    __syncthreads();

    int wave = t >> 6;      // 0..7
    int lane = t & 63;
    int eslot = lane >> 4;          // 0..3  (edge slot within 4-row load group)
    int cbase = (lane & 15) * 4;    // starting column (4 cols per lane)

    for (int ni = wave; ni < BK_NODES; ni += 8) {
        int node = b * BK_NODES + ni;
        if (node >= NN) continue;
        int d = cnt[ni];
        if (d > CAPN) d = CAPN;
        if (d == 0) {
            if (eslot == 0)
                *reinterpret_cast<float4*>(out + node * OUTD + cbase) =
                    make_float4(0.f, 0.f, 0.f, 0.f);
            continue;
        }
        float sdst = s_dst[node];

        // softmax phase: lane t owns edge t (d <= 64)
        int sid = 0;
        float ev = -INFINITY;
        if (lane < d) {
            sid = (int)seg[ni * CAPN + lane];        // LDS, stride-1
            float e0 = s_src[sid] + sdst;            // random 4B gather, cache-resident
            ev = e0 > 0.f ? e0 : 0.01f * e0;         // leaky_relu
        }
        int rowoff = sid * OUTD;

        float m = ev;
#pragma unroll
        for (int mm = 32; mm; mm >>= 1) m = fmaxf(m, __shfl_xor(m, mm, 64));
        float ex = (lane < d) ? __expf(ev - m) : 0.f;
        float l = ex;
#pragma unroll
        for (int mm = 32; mm; mm >>= 1) l += __shfl_xor(l, mm, 64);

        // aggregation: 4 edges per wave-load, uint2 (4 bf16 cols) per lane
        float a0 = 0.f, a1 = 0.f, a2 = 0.f, a3 = 0.f;
#pragma unroll 4
        for (int tt = 0; tt < d; tt += 4) {
            int e = tt + eslot;                      // < 64 always
            int ro = __shfl(rowoff, e, 64);          // bpermute
            float exv = __shfl(ex, e, 64);           // bpermute (0 if e >= d)
            uint2 v = *reinterpret_cast<const uint2*>(z16 + ro + cbase);
            float f0 = __uint_as_float(v.x << 16);
            float f1 = __uint_as_float(v.x & 0xFFFF0000u);
            float f2 = __uint_as_float(v.y << 16);
            float f3 = __uint_as_float(v.y & 0xFFFF0000u);
            a0 = fmaf(exv, f0, a0);
            a1 = fmaf(exv, f1, a1);
            a2 = fmaf(exv, f2, a2);
            a3 = fmaf(exv, f3, a3);
        }

        // reduce across the 4 edge slots (lanes ^16, ^32)
        a0 += __shfl_xor(a0, 16, 64); a0 += __shfl_xor(a0, 32, 64);
        a1 += __shfl_xor(a1, 16, 64); a1 += __shfl_xor(a1, 32, 64);
        a2 += __shfl_xor(a2, 16, 64); a2 += __shfl_xor(a2, 32, 64);
        a3 += __shfl_xor(a3, 16, 64); a3 += __shfl_xor(a3, 32, 64);

        if (eslot == 0) {                            // lanes 0..15: coalesced float4
            float inv = 1.f / l;
            *reinterpret_cast<float4*>(out + node * OUTD + cbase) =
                make_float4(a0 * inv, a1 * inv, a2 * inv, a3 * inv);
        }
    }
}

// ---------------- launcher ----------------
extern "C" void kernel_launch(void* const* d_in, const int* in_sizes, int n_in,
                              void* d_out, int out_size, void* d_ws, size_t ws_size,
                              hipStream_t stream)
{
    const float* h   = (const float*)d_in[0];
    const float* W   = (const float*)d_in[1];
    const float* a   = (const float*)d_in[2];
    const int*   src = (const int*)d_in[3];
    const int*   dst = (const int*)d_in[4];
    float* out = (float*)d_out;

    int* ws_i = (int*)d_ws;

    unsigned short* z16 = (unsigned short*)(ws_i + OFF_Z);
    float* s_src  = (float*)(ws_i + OFF_SSRC);
    float* s_dst  = (float*)(ws_i + OFF_SDST);
    int*   bcnt   = ws_i + OFF_BCNT;
    unsigned int* coarse = (unsigned int*)(ws_i + OFF_COARSE);

    hipMemsetAsync(bcnt, 0, NBUCK * sizeof(int), stream);

    // bin edges by 64-node bucket
    k_bin<<<BIN_BLOCKS, BIN_THREADS, 0, stream>>>(src, dst, bcnt, coarse);

    // z (bf16) via MFMA, s_src, s_dst
    k_zs<<<(NN + 63) / 64, 256, 0, stream>>>(h, W, a, z16, s_src, s_dst);

    // per-bucket LDS sub-CSR + softmax + aggregation (static grid)
    k_node<<<NBUCK, 512, 0, stream>>>(z16, coarse, bcnt, s_src, s_dst, out);
}